// Round 1
// baseline (1581.754 us; speedup 1.0000x reference)
//
#include <hip/hip_runtime.h>

#define NN 50000
#define NE 800000
// channels: 128 -> 128 -> 40

// ---------------- GEMM1: H1[50000,128] = x @ W1[128,128] ----------------
// 256 threads/block, 16 rows/block (50000 = 16*3125 exact).
// thread: q = tid&31 -> 4 consecutive output channels c=4q; rg = tid>>5 -> rows rg, rg+8.
__global__ __launch_bounds__(256) void gemm1_k(const float* __restrict__ x,
                                               const float* __restrict__ W,
                                               float* __restrict__ H1) {
    __shared__ float wl[128 * 128];   // W1 tile (whole matrix, 64 KB)
    __shared__ float xl[16 * 128];    // x tile (8 KB)
    const int tid = threadIdx.x;

    const float4* W4 = (const float4*)W;
    float4* wl4 = (float4*)wl;
#pragma unroll
    for (int i = 0; i < 16; ++i) wl4[tid + 256 * i] = W4[tid + 256 * i];

    const long row0 = (long)blockIdx.x * 16;
    const float4* x4 = (const float4*)(x + row0 * 128);
    float4* xl4 = (float4*)xl;
#pragma unroll
    for (int i = 0; i < 2; ++i) xl4[tid + 256 * i] = x4[tid + 256 * i];
    __syncthreads();

    const int q = tid & 31;    // float4 column index
    const int rg = tid >> 5;   // 0..7
    float4 acc0 = {0.f, 0.f, 0.f, 0.f};
    float4 acc1 = {0.f, 0.f, 0.f, 0.f};
    for (int k = 0; k < 128; ++k) {
        float4 w = wl4[k * 32 + q];
        float a0 = xl[rg * 128 + k];
        float a1 = xl[(rg + 8) * 128 + k];
        acc0.x += a0 * w.x; acc0.y += a0 * w.y; acc0.z += a0 * w.z; acc0.w += a0 * w.w;
        acc1.x += a1 * w.x; acc1.y += a1 * w.y; acc1.z += a1 * w.z; acc1.w += a1 * w.w;
    }
    float4* out4 = (float4*)(H1 + row0 * 128);
    out4[rg * 32 + q] = acc0;
    out4[(rg + 8) * 32 + q] = acc1;
}

// ---------------- scatter1: agg1[dst] += H1[src], 128 ch ----------------
// thread t handles (edge e = t>>5, float4 chunk q = t&31). 100000 blocks exact.
__global__ __launch_bounds__(256) void scatter1_k(const float* __restrict__ H1,
                                                  const int* __restrict__ src,
                                                  const int* __restrict__ dst,
                                                  float* __restrict__ agg) {
    const int t = blockIdx.x * 256 + threadIdx.x;
    const int e = t >> 5;
    const int q = t & 31;
    const int s = src[e];
    const int d = dst[e];
    float4 v = ((const float4*)(H1 + (long)s * 128))[q];
    float* a = agg + (long)d * 128 + q * 4;
    atomicAdd(a + 0, v.x);
    atomicAdd(a + 1, v.y);
    atomicAdd(a + 2, v.z);
    atomicAdd(a + 3, v.w);
}

// ---------------- relu+bias in place: h = relu(agg1 + b1) ----------------
__global__ __launch_bounds__(256) void relu_bias_k(float* __restrict__ h,
                                                   const float* __restrict__ b1) {
    const int i = blockIdx.x * 256 + threadIdx.x;  // float4 index, 1.6M total
    float4 v = ((float4*)h)[i];
    const int c = (i & 31) * 4;
    v.x = fmaxf(v.x + b1[c + 0], 0.f);
    v.y = fmaxf(v.y + b1[c + 1], 0.f);
    v.z = fmaxf(v.z + b1[c + 2], 0.f);
    v.w = fmaxf(v.w + b1[c + 3], 0.f);
    ((float4*)h)[i] = v;
}

// ---------------- GEMM2: H2[50000,40] = h @ W2[128,40] ----------------
__global__ __launch_bounds__(256) void gemm2_k(const float* __restrict__ h,
                                               const float* __restrict__ W2,
                                               float* __restrict__ H2) {
    __shared__ float wl[128 * 40];
    const int tid = threadIdx.x;
    for (int i = tid; i < 128 * 40 / 4; i += 256)
        ((float4*)wl)[i] = ((const float4*)W2)[i];
    __syncthreads();

    const int i = blockIdx.x * 256 + tid;
    if (i >= NN * 40) return;
    const int row = i / 40;
    const int c = i - row * 40;
    const float4* hrow = (const float4*)(h + (long)row * 128);
    float acc = 0.f;
#pragma unroll
    for (int k4 = 0; k4 < 32; ++k4) {
        float4 hv = hrow[k4];
        acc += hv.x * wl[(k4 * 4 + 0) * 40 + c];
        acc += hv.y * wl[(k4 * 4 + 1) * 40 + c];
        acc += hv.z * wl[(k4 * 4 + 2) * 40 + c];
        acc += hv.w * wl[(k4 * 4 + 3) * 40 + c];
    }
    H2[i] = acc;
}

// ---------------- scatter2: agg2[dst] += H2[src], 40 ch ----------------
__global__ __launch_bounds__(256) void scatter2_k(const float* __restrict__ H2,
                                                  const int* __restrict__ src,
                                                  const int* __restrict__ dst,
                                                  float* __restrict__ agg) {
    const long t = (long)blockIdx.x * 256 + threadIdx.x;  // 32M exact
    const int e = (int)(t / 40);
    const int c = (int)(t - (long)e * 40);
    const int s = src[e];
    const int d = dst[e];
    atomicAdd(agg + (long)d * 40 + c, H2[(long)s * 40 + c]);
}

// ---------------- bias + log_softmax over 40 channels ----------------
// one wave (64 lanes) per row, lanes >= 40 idle; 4 rows per block.
__global__ __launch_bounds__(256) void lsm_k(const float* __restrict__ agg2,
                                             const float* __restrict__ b2,
                                             float* __restrict__ out) {
    const int row = blockIdx.x * 4 + (threadIdx.x >> 6);
    const int lane = threadIdx.x & 63;
    float vb = 0.f;
    float v = -INFINITY;
    if (lane < 40) {
        vb = agg2[(long)row * 40 + lane] + b2[lane];
        v = vb;
    }
    float m = v;
#pragma unroll
    for (int off = 32; off; off >>= 1) m = fmaxf(m, __shfl_xor(m, off, 64));
    float e = (lane < 40) ? expf(vb - m) : 0.f;
    float s = e;
#pragma unroll
    for (int off = 32; off; off >>= 1) s += __shfl_xor(s, off, 64);
    if (lane < 40) out[(long)row * 40 + lane] = vb - m - logf(s);
}

extern "C" void kernel_launch(void* const* d_in, const int* in_sizes, int n_in,
                              void* d_out, int out_size, void* d_ws, size_t ws_size,
                              hipStream_t stream) {
    const float* x  = (const float*)d_in[0];
    const int*   ei = (const int*)d_in[1];   // [2, NE]: src = ei[0:NE], dst = ei[NE:2NE]
    const float* W1 = (const float*)d_in[2];
    const float* b1 = (const float*)d_in[3];
    const float* W2 = (const float*)d_in[4];
    const float* b2 = (const float*)d_in[5];
    const int* src = ei;
    const int* dst = ei + NE;

    float* H1   = (float*)d_ws;                 // 50000*128
    float* agg1 = H1   + (size_t)NN * 128;      // 50000*128 (becomes h after relu)
    float* H2   = agg1 + (size_t)NN * 128;      // 50000*40
    float* agg2 = H2   + (size_t)NN * 40;       // 50000*40
    float* out  = (float*)d_out;

    hipMemsetAsync(agg1, 0, (size_t)NN * 128 * sizeof(float), stream);
    hipMemsetAsync(agg2, 0, (size_t)NN * 40 * sizeof(float), stream);

    gemm1_k<<<3125, 256, 0, stream>>>(x, W1, H1);
    scatter1_k<<<100000, 256, 0, stream>>>(H1, src, dst, agg1);
    relu_bias_k<<<6250, 256, 0, stream>>>(agg1, b1);
    gemm2_k<<<7813, 256, 0, stream>>>(agg1, W2, H2);
    scatter2_k<<<125000, 256, 0, stream>>>(H2, src, dst, agg2);
    lsm_k<<<12500, 256, 0, stream>>>(agg2, b2, out);
}

// Round 2
// 278.355 us; speedup vs baseline: 5.6825x; 5.6825x over previous
//
#include <hip/hip_runtime.h>

#define NN 50000
#define NE 800000
#define NB 196   // ceil(NN/256)

// ---------------- GEMM1: H1[50000,128] = x @ W1[128,128] ----------------
__global__ __launch_bounds__(256) void gemm1_k(const float* __restrict__ x,
                                               const float* __restrict__ W,
                                               float* __restrict__ H1) {
    __shared__ float wl[128 * 128];   // whole W1, 64 KB
    __shared__ float xl[16 * 128];
    const int tid = threadIdx.x;

    const float4* W4 = (const float4*)W;
    float4* wl4 = (float4*)wl;
#pragma unroll
    for (int i = 0; i < 16; ++i) wl4[tid + 256 * i] = W4[tid + 256 * i];

    const long row0 = (long)blockIdx.x * 16;
    const float4* x4 = (const float4*)(x + row0 * 128);
    float4* xl4 = (float4*)xl;
#pragma unroll
    for (int i = 0; i < 2; ++i) xl4[tid + 256 * i] = x4[tid + 256 * i];
    __syncthreads();

    const int q = tid & 31;
    const int rg = tid >> 5;
    float4 acc0 = {0.f, 0.f, 0.f, 0.f};
    float4 acc1 = {0.f, 0.f, 0.f, 0.f};
    for (int k = 0; k < 128; ++k) {
        float4 w = wl4[k * 32 + q];
        float a0 = xl[rg * 128 + k];
        float a1 = xl[(rg + 8) * 128 + k];
        acc0.x += a0 * w.x; acc0.y += a0 * w.y; acc0.z += a0 * w.z; acc0.w += a0 * w.w;
        acc1.x += a1 * w.x; acc1.y += a1 * w.y; acc1.z += a1 * w.z; acc1.w += a1 * w.w;
    }
    float4* out4 = (float4*)(H1 + row0 * 128);
    out4[rg * 32 + q] = acc0;
    out4[(rg + 8) * 32 + q] = acc1;
}

// ---------------- CSR build ----------------
__global__ __launch_bounds__(256) void hist_k(const int* __restrict__ dst,
                                              int* __restrict__ count) {
    const int e = blockIdx.x * 256 + threadIdx.x;
    atomicAdd(&count[dst[e]], 1);
}

// per-256-chunk sums
__global__ __launch_bounds__(256) void reduce_k(const int* __restrict__ count,
                                                int* __restrict__ blocksum) {
    const int idx = blockIdx.x * 256 + threadIdx.x;
    int v = (idx < NN) ? count[idx] : 0;
#pragma unroll
    for (int off = 32; off; off >>= 1) v += __shfl_xor(v, off, 64);
    __shared__ int ws[4];
    if ((threadIdx.x & 63) == 0) ws[threadIdx.x >> 6] = v;
    __syncthreads();
    if (threadIdx.x == 0) blocksum[blockIdx.x] = ws[0] + ws[1] + ws[2] + ws[3];
}

// single block: exclusive scan of NB blocksums in place
__global__ __launch_bounds__(256) void scanblk_k(int* __restrict__ blocksum) {
    const int t = threadIdx.x;
    int v = (t < NB) ? blocksum[t] : 0;
    __shared__ int sm[256];
    sm[t] = v;
    __syncthreads();
#pragma unroll
    for (int off = 1; off < 256; off <<= 1) {
        int u = (t >= off) ? sm[t - off] : 0;
        __syncthreads();
        sm[t] += u;
        __syncthreads();
    }
    if (t < NB) blocksum[t] = sm[t] - v;   // exclusive
}

// per-chunk exclusive scan + chunk offset -> rowoff
__global__ __launch_bounds__(256) void scanfin_k(const int* __restrict__ count,
                                                 const int* __restrict__ blocksum,
                                                 int* __restrict__ rowoff) {
    const int t = threadIdx.x;
    const int idx = blockIdx.x * 256 + t;
    int v = (idx < NN) ? count[idx] : 0;
    __shared__ int sm[256];
    sm[t] = v;
    __syncthreads();
#pragma unroll
    for (int off = 1; off < 256; off <<= 1) {
        int u = (t >= off) ? sm[t - off] : 0;
        __syncthreads();
        sm[t] += u;
        __syncthreads();
    }
    if (idx < NN) rowoff[idx] = blocksum[blockIdx.x] + sm[t] - v;
    if (idx == 0) rowoff[NN] = NE;
}

__global__ __launch_bounds__(256) void fill_k(const int* __restrict__ src,
                                              const int* __restrict__ dst,
                                              const int* __restrict__ rowoff,
                                              int* __restrict__ cursor,
                                              int* __restrict__ eid) {
    const int e = blockIdx.x * 256 + threadIdx.x;
    const int d = dst[e];
    const int p = atomicAdd(&cursor[d], 1);
    eid[rowoff[d] + p] = src[e];
}

// ---------------- gather1 + bias + relu: h[n] = relu(sum_{j->n} H1[j] + b1) ----------------
// one wave per node; lane owns float2 (2 channels of 128)
__global__ __launch_bounds__(256) void gather1_k(const float* __restrict__ H1,
                                                 const int* __restrict__ rowoff,
                                                 const int* __restrict__ eid,
                                                 const float* __restrict__ b1,
                                                 float* __restrict__ h) {
    const int n = blockIdx.x * 4 + (threadIdx.x >> 6);
    const int lane = threadIdx.x & 63;
    const int beg = rowoff[n], end = rowoff[n + 1];
    const float2* H = (const float2*)H1;
    float2 acc = {0.f, 0.f};
    int k = beg;
    for (; k + 1 < end; k += 2) {
        const int s0 = eid[k], s1 = eid[k + 1];
        float2 v0 = H[s0 * 64 + lane];
        float2 v1 = H[s1 * 64 + lane];
        acc.x += v0.x + v1.x;
        acc.y += v0.y + v1.y;
    }
    if (k < end) {
        const int s0 = eid[k];
        float2 v0 = H[s0 * 64 + lane];
        acc.x += v0.x;
        acc.y += v0.y;
    }
    const float2 b = ((const float2*)b1)[lane];
    acc.x = fmaxf(acc.x + b.x, 0.f);
    acc.y = fmaxf(acc.y + b.y, 0.f);
    ((float2*)h)[n * 64 + lane] = acc;
}

// ---------------- GEMM2: H2[50000,40] = h @ W2[128,40] ----------------
__global__ __launch_bounds__(256) void gemm2_k(const float* __restrict__ h,
                                               const float* __restrict__ W2,
                                               float* __restrict__ H2) {
    __shared__ float wl[128 * 40];
    const int tid = threadIdx.x;
    for (int i = tid; i < 128 * 40 / 4; i += 256)
        ((float4*)wl)[i] = ((const float4*)W2)[i];
    __syncthreads();

    const int i = blockIdx.x * 256 + tid;
    if (i >= NN * 40) return;
    const int row = i / 40;
    const int c = i - row * 40;
    const float4* hrow = (const float4*)(h + (long)row * 128);
    float acc = 0.f;
#pragma unroll
    for (int k4 = 0; k4 < 32; ++k4) {
        float4 hv = hrow[k4];
        acc += hv.x * wl[(k4 * 4 + 0) * 40 + c];
        acc += hv.y * wl[(k4 * 4 + 1) * 40 + c];
        acc += hv.z * wl[(k4 * 4 + 2) * 40 + c];
        acc += hv.w * wl[(k4 * 4 + 3) * 40 + c];
    }
    H2[i] = acc;
}

// ---------------- gather2 + bias + log_softmax ----------------
// one wave per node; lanes 0..39 own one channel each
__global__ __launch_bounds__(256) void gather2_k(const float* __restrict__ H2,
                                                 const int* __restrict__ rowoff,
                                                 const int* __restrict__ eid,
                                                 const float* __restrict__ b2,
                                                 float* __restrict__ out) {
    const int n = blockIdx.x * 4 + (threadIdx.x >> 6);
    const int lane = threadIdx.x & 63;
    const int beg = rowoff[n], end = rowoff[n + 1];
    float acc = 0.f;
    if (lane < 40) {
        int k = beg;
        for (; k + 1 < end; k += 2) {
            const int s0 = eid[k], s1 = eid[k + 1];
            acc += H2[(long)s0 * 40 + lane] + H2[(long)s1 * 40 + lane];
        }
        if (k < end) acc += H2[(long)eid[k] * 40 + lane];
    }
    const float vb = acc + ((lane < 40) ? b2[lane] : 0.f);
    float m = (lane < 40) ? vb : -INFINITY;
#pragma unroll
    for (int off = 32; off; off >>= 1) m = fmaxf(m, __shfl_xor(m, off, 64));
    float e = (lane < 40) ? expf(vb - m) : 0.f;
#pragma unroll
    for (int off = 32; off; off >>= 1) e += __shfl_xor(e, off, 64);
    if (lane < 40) out[(long)n * 40 + lane] = vb - m - logf(e);
}

extern "C" void kernel_launch(void* const* d_in, const int* in_sizes, int n_in,
                              void* d_out, int out_size, void* d_ws, size_t ws_size,
                              hipStream_t stream) {
    const float* x  = (const float*)d_in[0];
    const int*   ei = (const int*)d_in[1];   // [2, NE]: src then dst
    const float* W1 = (const float*)d_in[2];
    const float* b1 = (const float*)d_in[3];
    const float* W2 = (const float*)d_in[4];
    const float* b2 = (const float*)d_in[5];
    const int* src = ei;
    const int* dst = ei + NE;

    float* H1   = (float*)d_ws;                    // NN*128
    float* h    = H1 + (size_t)NN * 128;           // NN*128
    float* H2   = h  + (size_t)NN * 128;           // NN*40
    int* count    = (int*)(H2 + (size_t)NN * 40);  // NN
    int* cursor   = count + NN;                    // NN
    int* rowoff   = cursor + NN;                   // NN+1
    int* blocksum = rowoff + NN + 1;               // 256
    int* eid      = blocksum + 256;                // NE
    float* out = (float*)d_out;

    hipMemsetAsync(count, 0, (size_t)NN * 2 * sizeof(int), stream);  // count + cursor

    gemm1_k<<<3125, 256, 0, stream>>>(x, W1, H1);
    hist_k<<<3125, 256, 0, stream>>>(dst, count);
    reduce_k<<<NB, 256, 0, stream>>>(count, blocksum);
    scanblk_k<<<1, 256, 0, stream>>>(blocksum);
    scanfin_k<<<NB, 256, 0, stream>>>(count, blocksum, rowoff);
    fill_k<<<3125, 256, 0, stream>>>(src, dst, rowoff, cursor, eid);
    gather1_k<<<12500, 256, 0, stream>>>(H1, rowoff, eid, b1, h);
    gemm2_k<<<7813, 256, 0, stream>>>(h, W2, H2);
    gather2_k<<<12500, 256, 0, stream>>>(H2, rowoff, eid, b2, out);
}